// Round 4
// baseline (1247.161 us; speedup 1.0000x reference)
//
#include <hip/hip_runtime.h>

#define NROWS 1000000
#define NT    31250      // 32-row tiles (1e6 / 32 exactly)
#define TPB   4          // tiles per wave-batch
#define NBATCH ((NT + TPB - 1) / TPB)   // 7813
#define MLP_BLOCKS 977   // 3908 waves -> ~2 batches/wave

typedef __bf16 bf16x8 __attribute__((ext_vector_type(8)));
typedef float  f32x16 __attribute__((ext_vector_type(16)));

// ---------------------------------------------------------------------------
// Kernel 1: per-tile (32 rows) nonzero counts. One row per thread, 32-lane
// shuffle reduce, lane 0 of each group stores.
// ---------------------------------------------------------------------------
__global__ __launch_bounds__(256) void count_kernel(
    const int* __restrict__ mask, int* __restrict__ counts) {
  int tid = threadIdx.x;
  int row = blockIdx.x * 256 + tid;
  int cnt = 0;
  if (row < NROWS) {
    const int4* mp = (const int4*)(mask + (long)row * 8);
    int4 a = mp[0], b = mp[1];
    cnt = (a.x != 0) + (a.y != 0) + (a.z != 0) + (a.w != 0) +
          (b.x != 0) + (b.y != 0) + (b.z != 0) + (b.w != 0);
  }
#pragma unroll
  for (int off = 1; off < 32; off <<= 1) cnt += __shfl_xor(cnt, off, 32);
  int tile = row >> 5;
  if ((tid & 31) == 0 && row < NROWS) counts[tile] = cnt;
}

// ---------------------------------------------------------------------------
// Kernel 2: exclusive scan of 31250 tile counts. Single block, 1024 threads,
// 32 counts/thread (static-indexed local array -> registers).
// ---------------------------------------------------------------------------
__global__ __launch_bounds__(1024) void scan_kernel(
    const int* __restrict__ counts, int* __restrict__ offs) {
  __shared__ int lds[1024];
  int tid = threadIdx.x;
  int base = tid * 32;
  int c[32];
  int s = 0;
#pragma unroll
  for (int i = 0; i < 32; ++i) {
    int idx = base + i;
    int v = (idx < NT) ? counts[idx] : 0;
    c[i] = s;  // exclusive within thread
    s += v;
  }
  lds[tid] = s;
  __syncthreads();
  for (int off = 1; off < 1024; off <<= 1) {
    int v = lds[tid];
    int add = (tid >= off) ? lds[tid - off] : 0;
    __syncthreads();
    lds[tid] = v + add;
    __syncthreads();
  }
  int tb = lds[tid] - s;  // exclusive base for this thread
#pragma unroll
  for (int i = 0; i < 32; ++i) {
    int idx = base + i;
    if (idx < NT) offs[idx] = tb + c[i];
  }
}

// ---------------------------------------------------------------------------
// Kernel 3: fused MFMA MLP + ordered compaction.
// Swapped operands: D[q][n] = (W0^T)[q][k] * X^T[k][n]; bias via C operand.
// Per wave: batch of 4 tiles (128 rows). A-frags/bias/w1 staged in LDS once
// per block; bias/w1 read per (d,qg) in the verified D reg-pattern.
// ---------------------------------------------------------------------------
__global__ __launch_bounds__(256) void mlp_kernel(
    const float* __restrict__ x, const int* __restrict__ mask,
    const float* __restrict__ w0, const float* __restrict__ b0,
    const float* __restrict__ w1, const float* __restrict__ b1,
    const int* __restrict__ tile_off, float* __restrict__ out) {
  __shared__ __bf16 sA[32 * 64 * 8];  // 32 frags x 64 lanes x 8 bf16 = 32 KB
  __shared__ float sB0[512];
  __shared__ float sW1[512];

  int tid = threadIdx.x;

  // ---- cooperative fill: W0^T fragments (bf16), b0, w1 ----
#pragma unroll
  for (int i = 0; i < 8; ++i) {
    int fi = tid * 8 + i;  // 0..2047 = frag(32) x lane(64)
    int frag = fi >> 6;
    int lane = fi & 63;
    int d = frag >> 2;
    int qg = (frag >> 1) & 1;
    int kc = frag & 1;
    int q = qg * 32 + (lane & 31);           // A row m -> hidden index
    int kbase = kc * 16 + (lane >> 5) * 8;   // k chunk per half-wave
    bf16x8 v;
#pragma unroll
    for (int j = 0; j < 8; ++j)
      v[j] = (__bf16)w0[d * 2048 + (kbase + j) * 64 + q];
    *(bf16x8*)&sA[fi * 8] = v;
  }
  if (tid < 128) {
    *(float4*)&sB0[tid * 4] = *(const float4*)&b0[tid * 4];
  } else {
    int t2 = tid - 128;
    *(float4*)&sW1[t2 * 4] = *(const float4*)&w1[t2 * 4];
  }
  __syncthreads();

  int l = tid & 63;
  int l31 = l & 31;
  int half = l >> 5;
  int wv = (blockIdx.x << 2) + (tid >> 6);
  int W = gridDim.x << 2;

  for (int b = wv; b < NBATCH; b += W) {
    int t0 = b * TPB;

    // ---- load x for 4 tiles -> B fragments (row n = l&31, k per half) ----
    bf16x8 Bf[TPB][2];
#pragma unroll
    for (int t = 0; t < TPB; ++t) {
      int tile = t0 + t;
      if (tile >= NT) tile = NT - 1;  // clamp; stores guarded later
      int row = tile * 32 + l31;
      const float* xp = x + row * 32 + half * 8;
#pragma unroll
      for (int kc = 0; kc < 2; ++kc) {
        float4 f0 = *(const float4*)(xp + kc * 16);
        float4 f1 = *(const float4*)(xp + kc * 16 + 4);
        bf16x8 v;
        v[0] = (__bf16)f0.x; v[1] = (__bf16)f0.y;
        v[2] = (__bf16)f0.z; v[3] = (__bf16)f0.w;
        v[4] = (__bf16)f1.x; v[5] = (__bf16)f1.y;
        v[6] = (__bf16)f1.z; v[7] = (__bf16)f1.w;
        Bf[t][kc] = v;
      }
    }

    float acc[8][TPB];
#pragma unroll
    for (int d = 0; d < 8; ++d)
#pragma unroll
      for (int t = 0; t < TPB; ++t) acc[d][t] = 0.f;

#pragma unroll
    for (int d = 0; d < 8; ++d) {
#pragma unroll
      for (int qg = 0; qg < 2; ++qg) {
        int fragbase = (d * 4 + qg * 2) * 512 + l * 8;
        bf16x8 A0 = *(const bf16x8*)&sA[fragbase];
        bf16x8 A1 = *(const bf16x8*)&sA[fragbase + 512];
        // bias (C) and w1 in the D register pattern:
        // reg r -> q = qg*32 + (r&3) + 8*(r>>2) + 4*half
        int qb = d * 64 + qg * 32 + half * 4;
        f32x16 C, W1r;
#pragma unroll
        for (int i = 0; i < 4; ++i) {
          float4 cv = *(const float4*)&sB0[qb + i * 8];
          float4 wv4 = *(const float4*)&sW1[qb + i * 8];
          C[i * 4 + 0] = cv.x; C[i * 4 + 1] = cv.y;
          C[i * 4 + 2] = cv.z; C[i * 4 + 3] = cv.w;
          W1r[i * 4 + 0] = wv4.x; W1r[i * 4 + 1] = wv4.y;
          W1r[i * 4 + 2] = wv4.z; W1r[i * 4 + 3] = wv4.w;
        }
#pragma unroll
        for (int t = 0; t < TPB; ++t) {
          f32x16 D = __builtin_amdgcn_mfma_f32_32x32x16_bf16(A0, Bf[t][0], C, 0, 0, 0);
          D = __builtin_amdgcn_mfma_f32_32x32x16_bf16(A1, Bf[t][1], D, 0, 0, 0);
          float a = acc[d][t];
#pragma unroll
          for (int r = 0; r < 16; ++r)
            a = fmaf(fmaxf(D[r], 0.f), W1r[r], a);
          acc[d][t] = a;
        }
      }
    }

    // ---- epilogue: mask, in-tile prefix, half-reduce, ordered scatter ----
#pragma unroll
    for (int t = 0; t < TPB; ++t) {
      int tile = t0 + t;
      bool valid = tile < NT;  // wave-uniform
      int ct = valid ? tile : NT - 1;
      int row = ct * 32 + l31;
      const int4* mp = (const int4*)(mask + (long)row * 8);
      int4 m0 = mp[0], m1 = mp[1];
      unsigned mb = (unsigned)((m0.x != 0) | ((m0.y != 0) << 1) |
                               ((m0.z != 0) << 2) | ((m0.w != 0) << 3) |
                               ((m1.x != 0) << 4) | ((m1.y != 0) << 5) |
                               ((m1.z != 0) << 6) | ((m1.w != 0) << 7));
      int cnt = __popc(mb);
      int incl = cnt;
#pragma unroll
      for (int off = 1; off < 32; off <<= 1) {
        int v = __shfl_up(incl, off, 32);
        if (l31 >= off) incl += v;
      }
      int pos = tile_off[ct] + (incl - cnt);
      float red[8];
#pragma unroll
      for (int d = 0; d < 8; ++d) {
        float s = acc[d][t];
        s += __shfl_xor(s, 32);
        red[d] = s + b1[d];
      }
      int base = pos + (half ? __popc(mb & 0xFu) : 0);
      unsigned nib = (mb >> (half * 4)) & 0xFu;
      if (valid) {
#pragma unroll
        for (int dd = 0; dd < 4; ++dd) {
          if ((nib >> dd) & 1u) {
            float v0 = red[dd], v1 = red[4 + dd];
            out[base] = half ? v1 : v0;  // static indices, cndmask select
            base++;
          }
        }
      }
    }
  }
}

extern "C" void kernel_launch(void* const* d_in, const int* in_sizes, int n_in,
                              void* d_out, int out_size, void* d_ws, size_t ws_size,
                              hipStream_t stream) {
  const float* x    = (const float*)d_in[0];
  const int*   mask = (const int*)d_in[1];
  const float* w0   = (const float*)d_in[2];
  const float* b0   = (const float*)d_in[3];
  const float* w1   = (const float*)d_in[4];
  const float* b1   = (const float*)d_in[5];
  float* out = (float*)d_out;

  int* counts = (int*)d_ws;
  int* offs   = counts + NT;

  count_kernel<<<(NROWS + 255) / 256, 256, 0, stream>>>(mask, counts);
  scan_kernel<<<1, 1024, 0, stream>>>(counts, offs);
  mlp_kernel<<<MLP_BLOCKS, 256, 0, stream>>>(x, mask, w0, b0, w1, b1, offs, out);
}